// Round 6
// baseline (2242.259 us; speedup 1.0000x reference)
//
#include <hip/hip_runtime.h>
#include <hip/hip_bf16.h>

#define N_NODES 100000
#define N_EDGES 1600000
#define EMB 128
#define D2 256
#define EDGE_F 16
#define BN_EPS 1e-5f
#define BK 64
#define SK 72   // LDS row stride (elements): 144 B -> max 2-way conflict (free)
#define NSCB 98 // scan blocks = ceil(N/1024)

typedef __hip_bfloat16 bf16;
typedef __attribute__((ext_vector_type(8))) short bf16x8;
typedef __attribute__((ext_vector_type(4))) float f32x4;

__device__ __forceinline__ bf16 f2b(float v) { return __float2bfloat16(v); }
__device__ __forceinline__ unsigned short f2bu(float v) {
    bf16 b = __float2bfloat16(v);
    return *(unsigned short*)&b;
}
__device__ __forceinline__ float bs2f(short s) {
    unsigned int u = ((unsigned int)(unsigned short)s) << 16;
    float f;
    __builtin_memcpy(&f, &u, 4);
    return f;
}

// ---------------- static device scratch ----------------
__device__ int   g_deg[N_NODES];
__device__ int   g_rowoff[N_NODES + 1];
__device__ int   g_cur[N_NODES];
__device__ int   g_csr[N_EDGES];
__device__ int   g_blksum[NSCB];
__device__ int   g_blkoff[NSCB];
__device__ float g_agg[N_NODES * EDGE_F];
__device__ float g_bnacc[2 * D2];
__device__ bf16  g_xb[(size_t)N_NODES * EMB];   // inter-layer node features (bf16)
__device__ bf16  g_t[(size_t)N_NODES * D2];     // GEMM1 A operand
__device__ float g_h1[(size_t)N_NODES * D2];    // fp32 for exact BN stats
__device__ bf16  g_w1b[5 * D2 * D2];
__device__ bf16  g_w2b[5 * EMB * D2];

// ---------------- one-time preprocessing ----------------

__global__ void k_init() {
    int i = blockIdx.x * blockDim.x + threadIdx.x;
    int stride = gridDim.x * blockDim.x;
    for (int j = i; j < N_NODES; j += stride) g_deg[j] = 0;
    for (int j = i; j < N_NODES * EDGE_F; j += stride) g_agg[j] = 0.f;
}

// all-layer weight conversion + x0 -> bf16
__global__ void k_prep(const float* __restrict__ x0, const float* __restrict__ W1,
                       const float* __restrict__ W2) {
    int i0 = blockIdx.x * blockDim.x + threadIdx.x;
    int st = gridDim.x * blockDim.x;
    for (int i = i0; i < 5 * D2 * D2; i += st) g_w1b[i] = f2b(W1[i]);
    for (int i = i0; i < 5 * EMB * D2; i += st) g_w2b[i] = f2b(W2[i]);
    for (int i = i0; i < N_NODES * EMB; i += st) g_xb[i] = f2b(x0[i]);
}

__global__ void k_edge(const int* __restrict__ ei, const float* __restrict__ ea) {
    int idx = blockIdx.x * blockDim.x + threadIdx.x;
    if (idx >= N_EDGES * EDGE_F) return;
    int e = idx >> 4;
    int f = idx & 15;
    int d = ei[N_EDGES + e];
    if (f == 0) atomicAdd(&g_deg[d], 1);
    atomicAdd(&g_agg[d * EDGE_F + f], ea[idx]);
}

__global__ void k_scan1() {
    __shared__ int s[1024];
    int tid = threadIdx.x;
    int i = blockIdx.x * 1024 + tid;
    int v = (i < N_NODES) ? g_deg[i] : 0;
    s[tid] = v;
    __syncthreads();
    for (int off = 1; off < 1024; off <<= 1) {
        int v2 = s[tid];
        if (tid >= off) v2 += s[tid - off];
        __syncthreads();
        s[tid] = v2;
        __syncthreads();
    }
    if (i < N_NODES) g_rowoff[i + 1] = s[tid];
    if (tid == 1023) g_blksum[blockIdx.x] = s[1023];
}

__global__ void k_scan2() {
    __shared__ int s[128];
    int tid = threadIdx.x;
    int v = (tid < NSCB) ? g_blksum[tid] : 0;
    s[tid] = v;
    __syncthreads();
    for (int off = 1; off < 128; off <<= 1) {
        int v2 = s[tid];
        if (tid >= off) v2 += s[tid - off];
        __syncthreads();
        s[tid] = v2;
        __syncthreads();
    }
    if (tid < NSCB) g_blkoff[tid] = s[tid] - v;   // exclusive
}

__global__ void k_scan3() {
    int i = blockIdx.x * blockDim.x + threadIdx.x;
    if (i == 0) g_rowoff[0] = 0;
    if (i < N_NODES) {
        int r = g_rowoff[i + 1] + g_blkoff[i >> 10];
        g_rowoff[i + 1] = r;
        g_cur[i] = r - g_deg[i];
    }
}

__global__ void k_fill(const int* __restrict__ ei) {
    int e = blockIdx.x * blockDim.x + threadIdx.x;
    if (e >= N_EDGES) return;
    int d = ei[N_EDGES + e];
    int pos = atomicAdd(&g_cur[d], 1);
    g_csr[pos] = ei[e];
}

// ---------------- per-layer kernels ----------------

// 16-lane group per node (16 nodes/block); lane owns 8 features (bf16x8, 16 B).
// Gather source is always bf16 g_xb. Block 0 zeroes bn accumulators.
__global__ __launch_bounds__(256) void k_agg(const float* __restrict__ EWl,
                                             const float* __restrict__ EBl) {
    int tid = threadIdx.x;
    if (blockIdx.x == 0) {
        g_bnacc[tid] = 0.f;
        g_bnacc[tid + 256] = 0.f;
    }
    int g = tid >> 4, lane = tid & 15;
    int v = blockIdx.x * 16 + g;
    __shared__ float sa[16][17];
    sa[g][lane] = g_agg[v * EDGE_F + lane];
    __syncthreads();

    const bf16x8* src = (const bf16x8*)g_xb;   // row stride 16 vectors
    float acc[8];
    bf16x8 own = src[(size_t)v * 16 + lane];
#pragma unroll
    for (int i = 0; i < 8; ++i) acc[i] = bs2f(own[i]);

    int r0 = g_rowoff[v], r1 = g_rowoff[v + 1];
    for (int base = r0; base < r1; base += 16) {
        int nb = r1 - base;
        if (nb > 16) nb = 16;
        int idx = (lane < nb) ? g_csr[base + lane] : 0;
        int j = 0;
        for (; j + 4 <= nb; j += 4) {
            int u0 = __shfl(idx, j, 16);
            int u1 = __shfl(idx, j + 1, 16);
            int u2 = __shfl(idx, j + 2, 16);
            int u3 = __shfl(idx, j + 3, 16);
            bf16x8 a0 = src[(size_t)u0 * 16 + lane];
            bf16x8 a1 = src[(size_t)u1 * 16 + lane];
            bf16x8 a2 = src[(size_t)u2 * 16 + lane];
            bf16x8 a3 = src[(size_t)u3 * 16 + lane];
#pragma unroll
            for (int i = 0; i < 8; ++i)
                acc[i] += (bs2f(a0[i]) + bs2f(a1[i])) + (bs2f(a2[i]) + bs2f(a3[i]));
        }
        for (; j < nb; ++j) {
            int u = __shfl(idx, j, 16);
            bf16x8 a0 = src[(size_t)u * 16 + lane];
#pragma unroll
            for (int i = 0; i < 8; ++i) acc[i] += bs2f(a0[i]);
        }
    }
    bf16x8 ov;
#pragma unroll
    for (int i = 0; i < 8; ++i) ((unsigned short*)&ov)[i] = f2bu(acc[i]);
    *(bf16x8*)&g_t[(size_t)v * D2 + lane * 8] = ov;

    // edge-embedding half: t[v,128+f] = sum_k agg[v,k]*EW[f,k] + (deg+1)*EB[f]
    float dp1 = (float)(r1 - r0 + 1);
    bf16x8 o2;
#pragma unroll
    for (int cc = 0; cc < 8; ++cc) {
        int f = lane * 8 + cc;
        float s2 = 0.f;
#pragma unroll
        for (int k = 0; k < EDGE_F; ++k) s2 += sa[g][k] * EWl[f * EDGE_F + k];
        s2 += dp1 * EBl[f];
        ((unsigned short*)&o2)[cc] = f2bu(s2);
    }
    *(bf16x8*)&g_t[(size_t)v * D2 + EMB + lane * 8] = o2;
}

// h1 = t @ W1^T + b1 via bf16 MFMA; BN column sums/sumsq fused into epilogue.
__global__ __launch_bounds__(256) void k_gemm1(const float* __restrict__ B1l, int l) {
    __shared__ __align__(16) short sA[128 * SK];
    __shared__ __align__(16) short sB[128 * SK];
    int tid = threadIdx.x;
    int r0 = blockIdx.x * 128;
    int c0 = blockIdx.y * 128;
    int w = tid >> 6, lane = tid & 63;
    int wr = (w >> 1) * 64, wc = (w & 1) * 64;
    int ln = lane & 15, lq = lane >> 4;
    f32x4 acc[4][4] = {};
    const uint4* gt = (const uint4*)g_t;
    const uint4* gw = (const uint4*)(g_w1b + (size_t)l * D2 * D2);
    for (int kk = 0; kk < D2; kk += BK) {
#pragma unroll
        for (int t = 0; t < 4; ++t) {
            int idx = tid + t * 256;
            int row = idx >> 3, seg = idx & 7;
            int r = r0 + row;
            uint4 val = make_uint4(0, 0, 0, 0);
            if (r < N_NODES) val = gt[(size_t)r * 32 + (kk >> 3) + seg];
            *(uint4*)&sA[row * SK + seg * 8] = val;
        }
#pragma unroll
        for (int t = 0; t < 4; ++t) {
            int idx = tid + t * 256;
            int row = idx >> 3, seg = idx & 7;
            *(uint4*)&sB[row * SK + seg * 8] = gw[(size_t)(c0 + row) * 32 + (kk >> 3) + seg];
        }
        __syncthreads();
#pragma unroll
        for (int k0 = 0; k0 < BK; k0 += 32) {
            bf16x8 af[4], bg[4];
#pragma unroll
            for (int a = 0; a < 4; ++a)
                af[a] = *(const bf16x8*)&sA[(wr + a * 16 + ln) * SK + k0 + lq * 8];
#pragma unroll
            for (int b = 0; b < 4; ++b)
                bg[b] = *(const bf16x8*)&sB[(wc + b * 16 + ln) * SK + k0 + lq * 8];
#pragma unroll
            for (int a = 0; a < 4; ++a)
#pragma unroll
                for (int b = 0; b < 4; ++b)
                    acc[a][b] = __builtin_amdgcn_mfma_f32_16x16x32_bf16(af[a], bg[b],
                                                                        acc[a][b], 0, 0, 0);
        }
        __syncthreads();
    }
    float sacc[4] = {0.f, 0.f, 0.f, 0.f};
    float qacc[4] = {0.f, 0.f, 0.f, 0.f};
#pragma unroll
    for (int a = 0; a < 4; ++a) {
#pragma unroll
        for (int r = 0; r < 4; ++r) {
            int row = r0 + wr + a * 16 + lq * 4 + r;
            if (row < N_NODES) {
#pragma unroll
                for (int b = 0; b < 4; ++b) {
                    int col = c0 + wc + b * 16 + ln;
                    float h = acc[a][b][r] + B1l[col];
                    g_h1[(size_t)row * D2 + col] = h;
                    sacc[b] += h;
                    qacc[b] += h * h;
                }
            }
        }
    }
#pragma unroll
    for (int b = 0; b < 4; ++b) {
        float s = sacc[b], q = qacc[b];
        s += __shfl_xor(s, 16); q += __shfl_xor(q, 16);
        s += __shfl_xor(s, 32); q += __shfl_xor(q, 32);
        if (lq == 0) {
            int col = c0 + wc + b * 16 + ln;
            atomicAdd(&g_bnacc[col], s);
            atomicAdd(&g_bnacc[D2 + col], q);
        }
    }
}

// out = [relu]( relu(h1*scale+shift) @ W2^T + b2 ) via bf16 MFMA.
// BN coef derivation (was k_bnfin) computed per-block from g_bnacc.
template <bool LAST>
__global__ __launch_bounds__(256) void k_gemm2(const float* __restrict__ BNWl,
                                               const float* __restrict__ BNBl,
                                               const float* __restrict__ B2l, int l,
                                               float* __restrict__ out) {
    __shared__ __align__(16) short sA[128 * SK];
    __shared__ __align__(16) short sB[128 * SK];
    __shared__ __align__(16) float sC[2 * D2];
    int tid = threadIdx.x;
    {
        float inv_n = 1.f / (float)N_NODES;
        float mean = g_bnacc[tid] * inv_n;
        float var = g_bnacc[D2 + tid] * inv_n - mean * mean;
        float scv = BNWl[tid] * rsqrtf(var + BN_EPS);
        sC[tid] = scv;
        sC[D2 + tid] = BNBl[tid] - mean * scv;
    }
    __syncthreads();
    int r0 = blockIdx.x * 128;
    int w = tid >> 6, lane = tid & 63;
    int wr = (w >> 1) * 64, wc = (w & 1) * 64;
    int ln = lane & 15, lq = lane >> 4;
    f32x4 acc[4][4] = {};
    const uint4* gw = (const uint4*)(g_w2b + (size_t)l * EMB * D2);
    for (int kk = 0; kk < D2; kk += BK) {
#pragma unroll
        for (int t = 0; t < 8; ++t) {
            int idx = tid + t * 256;
            int row = idx >> 4, seg = idx & 15;
            int r = r0 + row;
            int k = kk + seg * 4;
            ushort4 o = make_ushort4(0, 0, 0, 0);
            if (r < N_NODES) {
                float4 v = *(const float4*)&g_h1[(size_t)r * D2 + k];
                float4 s = *(const float4*)&sC[k];
                float4 h = *(const float4*)&sC[D2 + k];
                o.x = f2bu(fmaxf(v.x * s.x + h.x, 0.f));
                o.y = f2bu(fmaxf(v.y * s.y + h.y, 0.f));
                o.z = f2bu(fmaxf(v.z * s.z + h.z, 0.f));
                o.w = f2bu(fmaxf(v.w * s.w + h.w, 0.f));
            }
            *(ushort4*)&sA[row * SK + seg * 4] = o;
        }
#pragma unroll
        for (int t = 0; t < 4; ++t) {
            int idx = tid + t * 256;
            int row = idx >> 3, seg = idx & 7;
            *(uint4*)&sB[row * SK + seg * 8] = gw[(size_t)row * 32 + (kk >> 3) + seg];
        }
        __syncthreads();
#pragma unroll
        for (int k0 = 0; k0 < BK; k0 += 32) {
            bf16x8 af[4], bg[4];
#pragma unroll
            for (int a = 0; a < 4; ++a)
                af[a] = *(const bf16x8*)&sA[(wr + a * 16 + ln) * SK + k0 + lq * 8];
#pragma unroll
            for (int b = 0; b < 4; ++b)
                bg[b] = *(const bf16x8*)&sB[(wc + b * 16 + ln) * SK + k0 + lq * 8];
#pragma unroll
            for (int a = 0; a < 4; ++a)
#pragma unroll
                for (int b = 0; b < 4; ++b)
                    acc[a][b] = __builtin_amdgcn_mfma_f32_16x16x32_bf16(af[a], bg[b],
                                                                        acc[a][b], 0, 0, 0);
        }
        __syncthreads();
    }
#pragma unroll
    for (int a = 0; a < 4; ++a) {
#pragma unroll
        for (int r = 0; r < 4; ++r) {
            int row = r0 + wr + a * 16 + lq * 4 + r;
            if (row < N_NODES) {
#pragma unroll
                for (int b = 0; b < 4; ++b) {
                    int col = wc + b * 16 + ln;
                    float v = acc[a][b][r] + B2l[col];
                    if (LAST) out[(size_t)row * EMB + col] = v;
                    else      g_xb[(size_t)row * EMB + col] = f2b(fmaxf(v, 0.f));
                }
            }
        }
    }
}

extern "C" void kernel_launch(void* const* d_in, const int* in_sizes, int n_in,
                              void* d_out, int out_size, void* d_ws, size_t ws_size,
                              hipStream_t stream) {
    const float* x0 = (const float*)d_in[0];
    const float* ea = (const float*)d_in[1];
    const float* W1 = (const float*)d_in[2];
    const float* B1 = (const float*)d_in[3];
    const float* BNW = (const float*)d_in[4];
    const float* BNB = (const float*)d_in[5];
    const float* W2 = (const float*)d_in[6];
    const float* B2 = (const float*)d_in[7];
    const float* EW = (const float*)d_in[8];
    const float* EB = (const float*)d_in[9];
    const int* ei = (const int*)d_in[10];

    k_init<<<4096, 256, 0, stream>>>();
    k_prep<<<2048, 256, 0, stream>>>(x0, W1, W2);
    k_edge<<<(N_EDGES * EDGE_F + 255) / 256, 256, 0, stream>>>(ei, ea);
    k_scan1<<<NSCB, 1024, 0, stream>>>();
    k_scan2<<<1, 128, 0, stream>>>();
    k_scan3<<<(N_NODES + 255) / 256, 256, 0, stream>>>();
    k_fill<<<(N_EDGES + 255) / 256, 256, 0, stream>>>(ei);

    const int GB = (N_NODES + 127) / 128;   // 782
    for (int l = 0; l < 5; ++l) {
        const float* B1l = B1 + (size_t)l * D2;
        const float* BNWl = BNW + (size_t)l * D2;
        const float* BNBl = BNB + (size_t)l * D2;
        const float* B2l = B2 + (size_t)l * EMB;
        const float* EWl = EW + (size_t)l * EMB * EDGE_F;
        const float* EBl = EB + (size_t)l * EMB;

        k_agg<<<N_NODES / 16, 256, 0, stream>>>(EWl, EBl);
        k_gemm1<<<dim3(GB, 2), 256, 0, stream>>>(B1l, l);
        if (l < 4)
            k_gemm2<false><<<dim3(GB, 1), 256, 0, stream>>>(BNWl, BNBl, B2l, l, nullptr);
        else
            k_gemm2<true><<<dim3(GB, 1), 256, 0, stream>>>(BNWl, BNBl, B2l, l,
                                                           (float*)d_out);
    }
}